// Round 9
// baseline (75.882 us; speedup 1.0000x reference)
//
#include <hip/hip_runtime.h>

// DtN operator, M=64, N=32 RHS. One workgroup (8 waves) per RHS.
// Pipelined PCG (Ghysels-Vanroose, single fused dual-dot reduction per
// iteration) with global Chebyshev(DEG=8) preconditioner on [0.005, 2.0] of
// B = D^{-1/2} A D^{-1/2}. Thread t owns a 2x4 patch: rows {2rp, 2rp+1},
// cols 4*(t&15)..+3  (rp = t>>4). Intra-patch N/S are register-local;
// only N-of-top and S-of-bottom come from LDS (2 x b128 per stencil).
// E/W via intra-wave shuffles, wave/row-crossing garbage masked by zero
// boundary coefficients. Boundary points have all-zero coefs -> identity
// rows, no divergent branch. LDS stride 68 floats (16B-aligned, bank-uniform).
// Interval rationale: lambda_min(B) ~ 1-cos(pi/63) ~ 0.00124; [0.005,2]
// leaves only 4 sub-interval modes to CG (was ~11 at [0.015,2]).

#define BLK 512
#define NBP 252
#define DEG 8          // even: z1->ZA, z_DEG->ZB (gmv reads ZB)
#define MAXOUT 40
#define LDF 68

typedef float v4 __attribute__((ext_vector_type(4)));

static __device__ __forceinline__ float hmf(float x, float y) {
    float d = x + y;
    return d == 0.f ? 0.f : 2.f * x * y / d;
}

// clockwise Dirichlet embedding (top, right, bottom rev, left rev)
static __device__ __forceinline__ float embedf(const float* db, int i, int j) {
    if (i == 0 && j <= 62) return db[j];
    if (j == 63 && i <= 62) return db[63 + i];
    if (i == 63 && j >= 1)  return db[189 - j];
    return db[252 - i];   // j==0, i>=1
}

__global__ __launch_bounds__(BLK, 1) void dtn_gv(const float* __restrict__ dbc,
                                                 const float* __restrict__ a,
                                                 float* __restrict__ out) {
    __shared__ float ZA[64 * LDF], ZB[64 * LDF];
    __shared__ double redG[2][8], redD[2][8];

    const int t = threadIdx.x, l = t & 63, wid = t >> 6;
    const int rp = t >> 4;                 // row pair 0..31
    const int r0 = rp << 1, r1 = r0 + 1;
    const int cq = (t & 15) << 2;          // col base 0..60
    const int b0 = r0 * LDF + cq, b1 = r1 * LDF + cq;
    const int bn = (rp == 0 ? r0 : r0 - 1) * LDF + cq;    // N row of r0 (clamped)
    const int bs = (rp == 31 ? r1 : r1 + 1) * LDF + cq;   // S row of r1 (clamped)
    const float* db = dbc + blockIdx.x * NBP;

    float cE[8], cW[8], cN[8], cS[8], sD[8];
    float rr[8], uu[8], ww[8], xx[8], zz[8], qq[8], ss[8], pp[8], mm[8], nn[8];

    // ---- raw harmonic-mean coefficients + diagonal scale (registers) ----
    #pragma unroll
    for (int p = 0; p < 8; ++p) {
        const int i = (p < 4) ? r0 : r1, j = cq + (p & 3), gi = (i << 6) + j;
        float e = 0, w = 0, n_ = 0, s_ = 0, sv = 0;
        if (i > 0 && i < 63 && j > 0 && j < 63) {
            const float ac = a[gi];
            e  = hmf(ac, a[gi + 1]);
            w  = hmf(a[gi - 1], ac);
            n_ = hmf(a[gi - 64], ac);
            s_ = hmf(ac, a[gi + 64]);
            sv = 1.f / sqrtf(e + w + n_ + s_);
        }
        cE[p] = e; cW[p] = w; cN[p] = n_; cS[p] = s_; sD[p] = sv;
    }

    // ---- r0 = s .* (A_IB u_B): boundary-ring contributions, raw coefs ----
    #pragma unroll
    for (int p = 0; p < 8; ++p) {
        const int i = (p < 4) ? r0 : r1, j = cq + (p & 3);
        float acc = 0.f;
        if (sD[p] != 0.f) {
            if (i == 1)  acc += cN[p] * embedf(db, 0, j);
            if (i == 62) acc += cS[p] * embedf(db, 63, j);
            if (j == 1)  acc += cW[p] * embedf(db, i, 0);
            if (j == 62) acc += cE[p] * embedf(db, i, 63);
        }
        rr[p] = sD[p] * acc;
        xx[p] = zz[p] = qq[p] = ss[p] = pp[p] = 0.f;
    }

    auto store8 = [&](float* Z, const float* v) {
        v4 a0, a1;
        #pragma unroll
        for (int c = 0; c < 4; ++c) { a0[c] = v[c]; a1[c] = v[c + 4]; }
        *(v4*)&Z[b0] = a0; *(v4*)&Z[b1] = a1;
    };

    // ---- scale coefficients: c_dir *= sD_i * sD_neighbor ----
    // (boundary neighbors have sD=0 -> Dirichlet coupling eliminated)
    store8(ZA, sD);
    __syncthreads();
    {
        const float sw0 = __shfl_up(sD[3], 1, 64), se0 = __shfl_down(sD[0], 1, 64);
        const float sw1 = __shfl_up(sD[7], 1, 64), se1 = __shfl_down(sD[4], 1, 64);
        const v4 nv = *(const v4*)&ZA[bn];
        const v4 sv_ = *(const v4*)&ZA[bs];
        #pragma unroll
        for (int p = 0; p < 8; ++p) {
            const int c = p & 3;
            const float sn = (p < 4) ? nv[c]     : sD[p - 4];
            const float sb = (p < 4) ? sD[p + 4] : sv_[c];
            const float sw = (c == 0) ? ((p < 4) ? sw0 : sw1) : sD[p - 1];
            const float se = (c == 3) ? ((p < 4) ? se0 : se1) : sD[p + 1];
            cN[p] *= sD[p] * sn; cS[p] *= sD[p] * sb;
            cW[p] *= sD[p] * sw; cE[p] *= sD[p] * se;
        }
    }
    __syncthreads();   // ZA (sD) reads complete before cheb's z1 overwrites

    // ---- stencil: o = B in. N-of-top/S-of-bottom from LDS, rest registers.
    auto stencil = [&](const float* Zc, const float* in, float* o) {
        const float w0 = __shfl_up(in[3], 1, 64), e0 = __shfl_down(in[0], 1, 64);
        const float w1 = __shfl_up(in[7], 1, 64), e1 = __shfl_down(in[4], 1, 64);
        const v4 nv = *(const v4*)&Zc[bn];
        const v4 sv_ = *(const v4*)&Zc[bs];
        #pragma unroll
        for (int p = 0; p < 8; ++p) {
            const int c = p & 3;
            const float n_ = (p < 4) ? nv[c]     : in[p - 4];
            const float s_ = (p < 4) ? in[p + 4] : sv_[c];
            const float w_ = (c == 0) ? ((p < 4) ? w0 : w1) : in[p - 1];
            const float e_ = (c == 3) ? ((p < 4) ? e0 : e1) : in[p + 1];
            o[p] = in[p] - (cE[p] * e_ + cW[p] * w_ + cN[p] * n_ + cS[p] * s_);
        }
    };

    // ---- global Chebyshev preconditioner, [0.005, 2.0] ----
    const float thet = 1.0025f, delt = 0.9975f;
    const float sigc = thet / delt, invthet = 1.f / thet;

    // z_k stores: k odd -> ZA, k even -> ZB. Stencil k reads z_{k-1}'s buffer.
    auto cheb = [&](const float* rin, float* zo) {
        float d8[8], tp[8];
        #pragma unroll
        for (int p = 0; p < 8; ++p) { d8[p] = rin[p] * invthet; zo[p] = d8[p]; }
        store8(ZA, zo);                       // z1
        float rho = 1.f / sigc;
        #pragma unroll
        for (int k = 2; k <= DEG; ++k) {
            __syncthreads();
            stencil((k & 1) ? ZB : ZA, zo, tp);
            const float rho1 = 1.f / (2.f * sigc - rho);
            const float c1 = rho1 * rho, c2 = 2.f * rho1 / delt;
            #pragma unroll
            for (int p = 0; p < 8; ++p) { d8[p] = c1 * d8[p] + c2 * (rin[p] - tp[p]); zo[p] += d8[p]; }
            store8((k & 1) ? ZA : ZB, zo);    // z_k
            rho = rho1;
        }
    };

    // ---- setup: u0 = M^-1 r0 ; w0 = B u0 ----
    cheb(rr, uu);
    __syncthreads();          // publish z_DEG (= u0) in ZB
    stencil(ZB, uu, ww);

    // ---- pipelined PCG (GV): DEG barriers/iter, ONE fused reduction ----
    double gOld = 1.0, aOld = 1.0, gPrev = 1e300, stop = 0.0;
    int epar = 0, stg = 0;

    for (int it = 0; it < MAXOUT; ++it) {
        cheb(ww, mm);                        // m = M^-1 w (ends in ZB + regs)
        double pg = 0.0, pd = 0.0;
        #pragma unroll
        for (int p = 0; p < 8; ++p) { pg += (double)rr[p] * uu[p]; pd += (double)ww[p] * uu[p]; }
        #pragma unroll
        for (int off = 32; off > 0; off >>= 1) {
            pg += __shfl_down(pg, off, 64); pd += __shfl_down(pd, off, 64);
        }
        if (l == 0) { redG[epar][wid] = pg; redD[epar][wid] = pd; }
        __syncthreads();                     // slots + m(ZB) visible
        double G = 0.0, D = 0.0;
        #pragma unroll
        for (int w2 = 0; w2 < 8; ++w2) { G += redG[epar][w2]; D += redD[epar][w2]; }
        stencil(ZB, mm, nn);                 // n = B m

        double beta, alpha;
        if (it == 0) {
            if (!(G > 0.0)) break;
            beta = 0.0; alpha = G / D; stop = G * 1e-6;
        } else {
            if (!(G > stop)) break;          // converged / NaN guard (uniform)
            beta = G / gOld;
            const double den = D - beta * G / aOld;
            if (!(den > 0.0)) break;
            alpha = G / den;
        }
        bool last = false;
        if (it > 0) {
            if (G > 0.97 * gPrev) { if (++stg >= 3) last = true; }
            else stg = 0;
        }
        const float bf = (float)beta, af = (float)alpha;
        #pragma unroll
        for (int p = 0; p < 8; ++p) {
            zz[p] = nn[p] + bf * zz[p];
            qq[p] = mm[p] + bf * qq[p];
            ss[p] = ww[p] + bf * ss[p];
            pp[p] = uu[p] + bf * pp[p];
            xx[p] += af * pp[p];
            rr[p] -= af * ss[p];
            uu[p] -= af * qq[p];
            ww[p] -= af * zz[p];
        }
        gPrev = G; gOld = G; aOld = alpha; epar ^= 1;
        if (last) break;
    }

    // ---- stage final u = sD .* x (interior) / dbc (boundary) into ZA ----
    // (exit wave-uniform; all prior ZA reads were pre-reduction-barrier)
    float* P = ZA;
    {
        float fu[8];
        #pragma unroll
        for (int p = 0; p < 8; ++p) {
            const int i = (p < 4) ? r0 : r1, j = cq + (p & 3);
            if (i == 0 || i == 63 || j == 0 || j == 63) fu[p] = embedf(db, i, j);
            else fu[p] = sD[p] * xx[p];
        }
        store8(ZA, fu);
    }
    __syncthreads();

    // ---- Neumann flux (clockwise) + de-mean ----
    double v = 0.0;
    if (t < NBP) {
        const double Hi = 63.0;
        if (t == 0)        v = (double)a[0]  * 0.5 * (((double)P[0] - P[LDF]) + ((double)P[0] - P[1])) * Hi;
        else if (t <= 62)  v = (double)a[t]  * ((double)P[t] - P[LDF + t]) * Hi;
        else if (t == 63)  v = (double)a[63] * 0.5 * (((double)P[63] - P[LDF + 63]) + ((double)P[63] - P[62])) * Hi;
        else if (t <= 125) { const int i = t - 63;
                             v = (double)a[(i<<6)+63] * ((double)P[i*LDF+63] - P[i*LDF+62]) * Hi; }
        else if (t == 126) v = (double)a[4095] * 0.5 * (((double)P[63*LDF+63] - P[62*LDF+63]) + ((double)P[63*LDF+63] - P[63*LDF+62])) * Hi;
        else if (t <= 188) { const int j = 189 - t;
                             v = (double)a[4032+j] * ((double)P[63*LDF+j] - P[62*LDF+j]) * Hi; }
        else if (t == 189) v = (double)a[4032] * 0.5 * (((double)P[63*LDF] - P[62*LDF]) + ((double)P[63*LDF] - P[63*LDF+1])) * Hi;
        else               { const int i = 252 - t;
                             v = (double)a[i<<6] * ((double)P[i*LDF] - P[i*LDF+1]) * Hi; }
    }
    {
        double g = v;
        #pragma unroll
        for (int off = 32; off > 0; off >>= 1) g += __shfl_down(g, off, 64);
        if (l == 0) redG[0][wid] = g;
        __syncthreads();
        double tot = 0.0;
        #pragma unroll
        for (int w2 = 0; w2 < 8; ++w2) tot += redG[0][w2];
        if (t < NBP) out[blockIdx.x * NBP + t] = (float)(v - tot * (1.0 / 252.0));
    }
}

extern "C" void kernel_launch(void* const* d_in, const int* in_sizes, int n_in,
                              void* d_out, int out_size, void* d_ws, size_t ws_size,
                              hipStream_t stream) {
    const float* dbc = (const float*)d_in[0];   // (32, 252)
    const float* a   = (const float*)d_in[1];   // (64, 64)
    float* out = (float*)d_out;                 // (32, 252)
    dtn_gv<<<dim3(32), dim3(BLK), 0, stream>>>(dbc, a, out);
}

// Round 10
// 75.014 us; speedup vs baseline: 1.0116x; 1.0116x over previous
//
#include <hip/hip_runtime.h>

// DtN operator, M=64, N=32 RHS. One workgroup (8 waves) per RHS.
// Pipelined PCG (Ghysels-Vanroose) with global Chebyshev(DEG=8) preconditioner
// on [0.005, 2.0] of B = D^{-1/2} A D^{-1/2}. Thread t owns a 2x4 patch.
// R10: fp16 N/S halos inside cheb (ds b64 instead of b128; E/W + own patch stay
// fp32 registers). CG matvec stays exact: m published fp32 in MB; sD exchange
// through MB keeps B symmetric. Per-iter scaling sc=rsqrt(G) keeps fp16 in
// normal range. Broadcast-read reduction (1 slot read + shfl_xor tree).

#define BLK 512
#define NBP 252
#define DEG 8          // cheb: z1 store + k=2..8; z8 published fp32 in MB
#define MAXOUT 40
#define LDF 68

typedef float v4 __attribute__((ext_vector_type(4)));
typedef _Float16 h4 __attribute__((ext_vector_type(4)));

static __device__ __forceinline__ float hmf(float x, float y) {
    float d = x + y;
    return d == 0.f ? 0.f : 2.f * x * y / d;
}

// clockwise Dirichlet embedding (top, right, bottom rev, left rev)
static __device__ __forceinline__ float embedf(const float* db, int i, int j) {
    if (i == 0 && j <= 62) return db[j];
    if (j == 63 && i <= 62) return db[63 + i];
    if (i == 63 && j >= 1)  return db[189 - j];
    return db[252 - i];   // j==0, i>=1
}

__global__ __launch_bounds__(BLK, 1) void dtn_gv(const float* __restrict__ dbc,
                                                 const float* __restrict__ a,
                                                 float* __restrict__ out) {
    __shared__ _Float16 ZA[64 * LDF], ZB[64 * LDF];
    __shared__ float    MB[64 * LDF];
    __shared__ double   redG[2][8], redD[2][8];

    const int t = threadIdx.x, l = t & 63, wid = t >> 6;
    const int rp = t >> 4;                 // row pair 0..31
    const int r0 = rp << 1, r1 = r0 + 1;
    const int cq = (t & 15) << 2;          // col base 0..60
    const int b0 = r0 * LDF + cq, b1 = r1 * LDF + cq;
    const int bn = (rp == 0 ? r0 : r0 - 1) * LDF + cq;    // N row of r0 (clamped)
    const int bs = (rp == 31 ? r1 : r1 + 1) * LDF + cq;   // S row of r1 (clamped)
    const float* db = dbc + blockIdx.x * NBP;

    float nE[8], nW[8], nN[8], nS[8], sD[8];   // negated scaled coefficients
    float rr[8], uu[8], ww[8], xx[8], zz[8], qq[8], ss[8], pp[8], mm[8], nn[8];

    // ---- raw harmonic-mean coefficients + diagonal scale (registers) ----
    #pragma unroll
    for (int p = 0; p < 8; ++p) {
        const int i = (p < 4) ? r0 : r1, j = cq + (p & 3), gi = (i << 6) + j;
        float e = 0, w = 0, n_ = 0, s_ = 0, sv = 0;
        if (i > 0 && i < 63 && j > 0 && j < 63) {
            const float ac = a[gi];
            e  = hmf(ac, a[gi + 1]);
            w  = hmf(a[gi - 1], ac);
            n_ = hmf(a[gi - 64], ac);
            s_ = hmf(ac, a[gi + 64]);
            sv = 1.f / sqrtf(e + w + n_ + s_);
        }
        nE[p] = e; nW[p] = w; nN[p] = n_; nS[p] = s_; sD[p] = sv;
    }

    // ---- r0 = s .* (A_IB u_B): boundary-ring contributions, raw (+) coefs ----
    #pragma unroll
    for (int p = 0; p < 8; ++p) {
        const int i = (p < 4) ? r0 : r1, j = cq + (p & 3);
        float acc = 0.f;
        if (sD[p] != 0.f) {
            if (i == 1)  acc += nN[p] * embedf(db, 0, j);
            if (i == 62) acc += nS[p] * embedf(db, 63, j);
            if (j == 1)  acc += nW[p] * embedf(db, i, 0);
            if (j == 62) acc += nE[p] * embedf(db, i, 63);
        }
        rr[p] = sD[p] * acc;
        xx[p] = zz[p] = qq[p] = ss[p] = pp[p] = 0.f;
    }

    auto storeF = [&](float* Z, const float* v) {
        v4 a0, a1;
        #pragma unroll
        for (int c = 0; c < 4; ++c) { a0[c] = v[c]; a1[c] = v[c + 4]; }
        *(v4*)&Z[b0] = a0; *(v4*)&Z[b1] = a1;
    };
    auto storeH = [&](_Float16* Z, const float* v) {
        h4 a0, a1;
        #pragma unroll
        for (int c = 0; c < 4; ++c) { a0[c] = (_Float16)v[c]; a1[c] = (_Float16)v[c + 4]; }
        *(h4*)&Z[b0] = a0; *(h4*)&Z[b1] = a1;
    };

    // ---- scale coefficients via fp32 MB exchange (keeps B exactly symmetric),
    //      then NEGATE (stencil becomes 4 FMAs) ----
    storeF(MB, sD);
    __syncthreads();
    {
        const float sw0 = __shfl_up(sD[3], 1, 64), se0 = __shfl_down(sD[0], 1, 64);
        const float sw1 = __shfl_up(sD[7], 1, 64), se1 = __shfl_down(sD[4], 1, 64);
        const v4 nv = *(const v4*)&MB[bn];
        const v4 sv_ = *(const v4*)&MB[bs];
        #pragma unroll
        for (int p = 0; p < 8; ++p) {
            const int c = p & 3;
            const float sn = (p < 4) ? nv[c]     : sD[p - 4];
            const float sb = (p < 4) ? sD[p + 4] : sv_[c];
            const float sw = (c == 0) ? ((p < 4) ? sw0 : sw1) : sD[p - 1];
            const float se = (c == 3) ? ((p < 4) ? se0 : se1) : sD[p + 1];
            nN[p] *= -sD[p] * sn; nS[p] *= -sD[p] * sb;
            nW[p] *= -sD[p] * sw; nE[p] *= -sD[p] * se;
        }
    }
    // (no barrier needed here: next MB write is cheb k=DEG, separated by its
    //  internal barriers from every wave's MB read above)

    // ---- stencils: o = B in = in + Σ nC·neighbor (nC negated) ----
    auto stencilH = [&](const _Float16* Zc, const float* in, float* o) {
        const float w0 = __shfl_up(in[3], 1, 64), e0 = __shfl_down(in[0], 1, 64);
        const float w1 = __shfl_up(in[7], 1, 64), e1 = __shfl_down(in[4], 1, 64);
        const h4 nh = *(const h4*)&Zc[bn];
        const h4 sh = *(const h4*)&Zc[bs];
        #pragma unroll
        for (int p = 0; p < 8; ++p) {
            const int c = p & 3;
            const float n_ = (p < 4) ? (float)nh[c] : in[p - 4];
            const float s_ = (p < 4) ? in[p + 4]    : (float)sh[c];
            const float w_ = (c == 0) ? ((p < 4) ? w0 : w1) : in[p - 1];
            const float e_ = (c == 3) ? ((p < 4) ? e0 : e1) : in[p + 1];
            o[p] = fmaf(nE[p], e_, fmaf(nW[p], w_, fmaf(nN[p], n_, fmaf(nS[p], s_, in[p]))));
        }
    };
    auto stencilF = [&](const float* Zc, const float* in, float* o) {
        const float w0 = __shfl_up(in[3], 1, 64), e0 = __shfl_down(in[0], 1, 64);
        const float w1 = __shfl_up(in[7], 1, 64), e1 = __shfl_down(in[4], 1, 64);
        const v4 nv = *(const v4*)&Zc[bn];
        const v4 sv_ = *(const v4*)&Zc[bs];
        #pragma unroll
        for (int p = 0; p < 8; ++p) {
            const int c = p & 3;
            const float n_ = (p < 4) ? nv[c]     : in[p - 4];
            const float s_ = (p < 4) ? in[p + 4] : sv_[c];
            const float w_ = (c == 0) ? ((p < 4) ? w0 : w1) : in[p - 1];
            const float e_ = (c == 3) ? ((p < 4) ? e0 : e1) : in[p + 1];
            o[p] = fmaf(nE[p], e_, fmaf(nW[p], w_, fmaf(nN[p], n_, fmaf(nS[p], s_, in[p]))));
        }
    };

    // ---- global Chebyshev preconditioner, [0.005, 2.0], fp16 internal halos.
    // Input scaled by sc (keeps fp16 in normal range); z_DEG unscaled by isc
    // and published fp32 in MB for the exact outer matvec.
    const float thet = 1.0025f, delt = 0.9975f;
    const float sigc = thet / delt, invthet = 1.f / thet;

    auto cheb = [&](const float* rin, float* zo, float sc, float isc) {
        float rs[8], d8[8], tp[8];
        #pragma unroll
        for (int p = 0; p < 8; ++p) { rs[p] = rin[p] * sc; d8[p] = rs[p] * invthet; zo[p] = d8[p]; }
        storeH(ZA, zo);                       // z1
        float rho = 1.f / sigc;
        #pragma unroll
        for (int k = 2; k <= DEG; ++k) {
            __syncthreads();
            stencilH((k & 1) ? ZB : ZA, zo, tp);
            const float rho1 = 1.f / (2.f * sigc - rho);
            const float c1 = rho1 * rho, c2 = 2.f * rho1 / delt;
            #pragma unroll
            for (int p = 0; p < 8; ++p) { d8[p] = c1 * d8[p] + c2 * (rs[p] - tp[p]); zo[p] += d8[p]; }
            if (k < DEG) {
                storeH((k & 1) ? ZA : ZB, zo);    // z_k fp16
            } else {
                #pragma unroll
                for (int p = 0; p < 8; ++p) zo[p] *= isc;   // unscale
                storeF(MB, zo);                   // publish m fp32 (exact matvec)
            }
            rho = rho1;
        }
    };

    // ---- setup: u0 = M^-1 r0 ; w0 = B u0 ----
    cheb(rr, uu, 1.f, 1.f);
    __syncthreads();          // publish MB (= u0)
    stencilF(MB, uu, ww);

    // ---- pipelined PCG (GV): DEG barriers/iter, ONE fused reduction ----
    double gOld = 1.0, aOld = 1.0, gPrev = 1e300, stop = 0.0;
    int epar = 0, stg = 0;
    float scv = 1.f, iscv = 1.f;

    for (int it = 0; it < MAXOUT; ++it) {
        cheb(ww, mm, scv, iscv);             // m = M^-1 w (ends fp32 in MB + regs)
        double pg = 0.0, pd = 0.0;
        #pragma unroll
        for (int p = 0; p < 8; ++p) { pg += (double)rr[p] * uu[p]; pd += (double)ww[p] * uu[p]; }
        #pragma unroll
        for (int off = 32; off > 0; off >>= 1) {
            pg += __shfl_down(pg, off, 64); pd += __shfl_down(pd, off, 64);
        }
        if (l == 0) { redG[epar][wid] = pg; redD[epar][wid] = pd; }
        __syncthreads();                     // slots + m(MB) visible
        // broadcast-read reduction: 1 slot read + xor tree (same-addr reads broadcast)
        double G = redG[epar][l & 7], D = redD[epar][l & 7];
        #pragma unroll
        for (int off = 1; off < 8; off <<= 1) {
            G += __shfl_xor(G, off, 64); D += __shfl_xor(D, off, 64);
        }
        stencilF(MB, mm, nn);                // n = B m  (exact fp32)

        double beta, alpha;
        if (it == 0) {
            if (!(G > 0.0)) break;
            beta = 0.0; alpha = G / D; stop = G * 1e-6;
        } else {
            if (!(G > stop)) break;          // converged / NaN guard (uniform)
            beta = G / gOld;
            const double den = D - beta * G / aOld;
            if (!(den > 0.0)) break;
            alpha = G / den;
        }
        bool last = false;
        if (it > 0) {
            if (G > 0.97 * gPrev) { if (++stg >= 3) last = true; }
            else stg = 0;
        }
        const float bf = (float)beta, af = (float)alpha;
        #pragma unroll
        for (int p = 0; p < 8; ++p) {
            zz[p] = nn[p] + bf * zz[p];
            qq[p] = mm[p] + bf * qq[p];
            ss[p] = ww[p] + bf * ss[p];
            pp[p] = uu[p] + bf * pp[p];
            xx[p] += af * pp[p];
            rr[p] -= af * ss[p];
            uu[p] -= af * qq[p];
            ww[p] -= af * zz[p];
        }
        gPrev = G; gOld = G; aOld = alpha; epar ^= 1;
        // rescale next cheb input to O(1) in fp16
        const float gf = (float)G;
        scv = (gf > 0.f) ? rsqrtf(gf) : 1.f;
        iscv = (gf > 0.f) ? sqrtf(gf) : 1.f;
        if (last) break;
    }

    // ---- stage final u = sD .* x (interior) / dbc (boundary) into MB ----
    __syncthreads();   // drain all waves' gmv reads of MB before overwrite
    {
        float fu[8];
        #pragma unroll
        for (int p = 0; p < 8; ++p) {
            const int i = (p < 4) ? r0 : r1, j = cq + (p & 3);
            if (i == 0 || i == 63 || j == 0 || j == 63) fu[p] = embedf(db, i, j);
            else fu[p] = sD[p] * xx[p];
        }
        storeF(MB, fu);
    }
    __syncthreads();
    const float* P = MB;

    // ---- Neumann flux (clockwise) + de-mean ----
    double v = 0.0;
    if (t < NBP) {
        const double Hi = 63.0;
        if (t == 0)        v = (double)a[0]  * 0.5 * (((double)P[0] - P[LDF]) + ((double)P[0] - P[1])) * Hi;
        else if (t <= 62)  v = (double)a[t]  * ((double)P[t] - P[LDF + t]) * Hi;
        else if (t == 63)  v = (double)a[63] * 0.5 * (((double)P[63] - P[LDF + 63]) + ((double)P[63] - P[62])) * Hi;
        else if (t <= 125) { const int i = t - 63;
                             v = (double)a[(i<<6)+63] * ((double)P[i*LDF+63] - P[i*LDF+62]) * Hi; }
        else if (t == 126) v = (double)a[4095] * 0.5 * (((double)P[63*LDF+63] - P[62*LDF+63]) + ((double)P[63*LDF+63] - P[63*LDF+62])) * Hi;
        else if (t <= 188) { const int j = 189 - t;
                             v = (double)a[4032+j] * ((double)P[63*LDF+j] - P[62*LDF+j]) * Hi; }
        else if (t == 189) v = (double)a[4032] * 0.5 * (((double)P[63*LDF] - P[62*LDF]) + ((double)P[63*LDF] - P[63*LDF+1])) * Hi;
        else               { const int i = 252 - t;
                             v = (double)a[i<<6] * ((double)P[i*LDF] - P[i*LDF+1]) * Hi; }
    }
    {
        double g = v;
        #pragma unroll
        for (int off = 32; off > 0; off >>= 1) g += __shfl_down(g, off, 64);
        if (l == 0) redG[0][wid] = g;
        __syncthreads();
        double tot = 0.0;
        #pragma unroll
        for (int w2 = 0; w2 < 8; ++w2) tot += redG[0][w2];
        if (t < NBP) out[blockIdx.x * NBP + t] = (float)(v - tot * (1.0 / 252.0));
    }
}

extern "C" void kernel_launch(void* const* d_in, const int* in_sizes, int n_in,
                              void* d_out, int out_size, void* d_ws, size_t ws_size,
                              hipStream_t stream) {
    const float* dbc = (const float*)d_in[0];   // (32, 252)
    const float* a   = (const float*)d_in[1];   // (64, 64)
    float* out = (float*)d_out;                 // (32, 252)
    dtn_gv<<<dim3(32), dim3(BLK), 0, stream>>>(dbc, a, out);
}